// Round 1
// baseline (460.209 us; speedup 1.0000x reference)
//
#include <hip/hip_runtime.h>
#include <hip/hip_bf16.h>

typedef __bf16 bf16x8 __attribute__((ext_vector_type(8)));
typedef float f32x4 __attribute__((ext_vector_type(4)));

__device__ inline unsigned short f2bf(float f) {
    unsigned u = __builtin_bit_cast(unsigned, f);
    unsigned r = (u + 0x7fffu + ((u >> 16) & 1u)) >> 16;
    return (unsigned short)r;
}
__device__ inline float bf2f(unsigned short h) {
    unsigned u = ((unsigned)h) << 16;
    return __builtin_bit_cast(float, u);
}

// K0: cast w2 -> bf16; compute segment offsets
__global__ __launch_bounds__(256) void k0_prep(const float* __restrict__ w2,
                                               unsigned short* __restrict__ w2b,
                                               const int* __restrict__ length,
                                               int* __restrict__ off) {
    int i = blockIdx.x * 256 + threadIdx.x;
    if (i < 1024 * 256) w2b[i] = f2bf(w2[i]);
    if (blockIdx.x == 0 && threadIdx.x == 0) {
        int acc = 0;
        for (int b = 0; b < 16; b++) { off[b] = acc; acc += length[b]; }
        off[16] = acc;
    }
}

// K1: att1 = relu(bn1(x @ w1.T + b1)) -> bf16 [N,256]
__global__ __launch_bounds__(256) void k1_gemm1(const float* __restrict__ x,
                                                const float* __restrict__ w1,
                                                const float* __restrict__ b1,
                                                const float* __restrict__ g1,
                                                const float* __restrict__ be1,
                                                const float* __restrict__ m1,
                                                const float* __restrict__ v1,
                                                unsigned short* __restrict__ att1) {
    __shared__ float xs[64][33];
    int tid = threadIdx.x;
    int row0 = blockIdx.x * 64;
    for (int i = tid; i < 64 * 32; i += 256) {
        int rr = i >> 5, c = i & 31;
        xs[rr][c] = x[(row0 + rr) * 32 + c];
    }
    __syncthreads();
    int j = tid;  // output channel 0..255
    float w[32];
#pragma unroll
    for (int c = 0; c < 32; c++) w[c] = w1[j * 32 + c];
    float s = g1[j] * rsqrtf(v1[j] + 1e-5f);
    float bias = (b1[j] - m1[j]) * s + be1[j];
    for (int rr = 0; rr < 64; rr++) {
        float acc = 0.f;
#pragma unroll
        for (int c = 0; c < 32; c++) acc = fmaf(xs[rr][c], w[c], acc);
        float t = fmaf(acc, s, bias);
        att1[(row0 + rr) * 256 + j] = f2bf(fmaxf(t, 0.f));
    }
}

// K2: e = exp(relu(bn2(att1 @ w2.T + b2))) -> bf16 [N,1024], MFMA bf16
__global__ __launch_bounds__(256) void k2_gemm2(const unsigned short* __restrict__ att1,
                                                const unsigned short* __restrict__ w2b,
                                                const float* __restrict__ b2,
                                                const float* __restrict__ g2,
                                                const float* __restrict__ be2,
                                                const float* __restrict__ m2,
                                                const float* __restrict__ v2,
                                                unsigned short* __restrict__ e) {
    int tid = threadIdx.x;
    int lane = tid & 63;
    int wave = tid >> 6;
    int wr = wave >> 1, wc = wave & 1;
    int bn = blockIdx.x & 255;   // 32768/128 = 256 row tiles
    int bk = blockIdx.x >> 8;    // 1024/128 = 8 col tiles
    int row0 = bn * 128 + wr * 64;
    int col0 = bk * 128 + wc * 64;
    int lr = lane & 15;
    int lk = (lane >> 4) * 8;
    f32x4 acc[4][4] = {};
    for (int ks = 0; ks < 256; ks += 32) {
        bf16x8 a[4], b[4];
#pragma unroll
        for (int m = 0; m < 4; m++)
            a[m] = *(const bf16x8*)(const void*)(att1 + (size_t)(row0 + m * 16 + lr) * 256 + ks + lk);
#pragma unroll
        for (int n = 0; n < 4; n++)
            b[n] = *(const bf16x8*)(const void*)(w2b + (size_t)(col0 + n * 16 + lr) * 256 + ks + lk);
#pragma unroll
        for (int m = 0; m < 4; m++)
#pragma unroll
            for (int n = 0; n < 4; n++)
                acc[m][n] = __builtin_amdgcn_mfma_f32_16x16x32_bf16(a[m], b[n], acc[m][n], 0, 0, 0);
    }
    int cr = (lane >> 4) * 4;
    int cc = lane & 15;
#pragma unroll
    for (int n = 0; n < 4; n++) {
        int k = col0 + n * 16 + cc;
        float s = g2[k] * rsqrtf(v2[k] + 1e-5f);
        float bias = (b2[k] - m2[k]) * s + be2[k];
#pragma unroll
        for (int m = 0; m < 4; m++) {
#pragma unroll
            for (int rg = 0; rg < 4; rg++) {
                int row = row0 + m * 16 + cr + rg;
                float t = fmaf(acc[m][n][rg], s, bias);
                t = fmaxf(t, 0.f);               // relu THEN exp: exp(0)=1 for negatives
                e[(size_t)row * 1024 + k] = f2bf(__expf(t));
            }
        }
    }
}

// K3: per-segment S = sum(e), P = sum(e*x); out2[b][k*32+c] = P/(S*len)
__global__ __launch_bounds__(256) void k3_pool(const unsigned short* __restrict__ e,
                                               const float* __restrict__ x,
                                               const int* __restrict__ off,
                                               float* __restrict__ out2) {
    int b = blockIdx.x >> 7;
    int kt = blockIdx.x & 127;
    int tid = threadIdx.x;
    int kl = tid >> 5, c = tid & 31;
    int k = kt * 8 + kl;
    int n0 = off[b], n1 = off[b + 1];
    float P = 0.f, S = 0.f;
    int n = n0;
    for (; n + 4 <= n1; n += 4) {
#pragma unroll
        for (int u = 0; u < 4; u++) {
            float ev = bf2f(e[(size_t)(n + u) * 1024 + k]);
            P = fmaf(ev, x[(n + u) * 32 + c], P);
            S += ev;
        }
    }
    for (; n < n1; n++) {
        float ev = bf2f(e[(size_t)n * 1024 + k]);
        P = fmaf(ev, x[n * 32 + c], P);
        S += ev;
    }
    float len = (float)(n1 - n0);
    out2[b * 32768 + k * 32 + c] = P / (S * len);
}

// K4: r = bn3(out2 @ fcw.T + fcb)  [16,256]; block = 8 j's x 4 b's
__global__ __launch_bounds__(256) void k4_fc(const float* __restrict__ out2,
                                             const float* __restrict__ fcw,
                                             const float* __restrict__ fcb,
                                             const float* __restrict__ g3,
                                             const float* __restrict__ be3,
                                             const float* __restrict__ m3,
                                             const float* __restrict__ v3,
                                             float* __restrict__ r) {
    int jt = blockIdx.x >> 2;   // 0..31 (8 j's each)
    int bg = blockIdx.x & 3;    // 0..3  (4 b's each)
    int tid = threadIdx.x;
    float acc[4][8] = {};
    for (int i = 0; i < 128; i++) {
        int d = i * 256 + tid;
        float ov[4];
#pragma unroll
        for (int bb = 0; bb < 4; bb++) ov[bb] = out2[(bg * 4 + bb) * 32768 + d];
#pragma unroll
        for (int jj = 0; jj < 8; jj++) {
            float wv = fcw[(size_t)(jt * 8 + jj) * 32768 + d];
#pragma unroll
            for (int bb = 0; bb < 4; bb++) acc[bb][jj] = fmaf(ov[bb], wv, acc[bb][jj]);
        }
    }
    __shared__ float red[32][257];
#pragma unroll
    for (int bb = 0; bb < 4; bb++)
#pragma unroll
        for (int jj = 0; jj < 8; jj++)
            red[bb * 8 + jj][tid] = acc[bb][jj];
    __syncthreads();
    int row = tid >> 3, sg = tid & 7;
    float s = 0.f;
    for (int t = sg; t < 256; t += 8) s += red[row][t];
#pragma unroll
    for (int o = 4; o > 0; o >>= 1) s += __shfl_down(s, o, 8);
    if (sg == 0) {
        int bb = row >> 3, jj = row & 7;
        int j = jt * 8 + jj;
        int bidx = bg * 4 + bb;
        float sc = g3[j] * rsqrtf(v3[j] + 1e-5f);
        r[bidx * 256 + j] = (s + fcb[j] - m3[j]) * sc + be3[j];
    }
}

// K5: L2-normalize rows of r -> out
__global__ __launch_bounds__(256) void k5_norm(const float* __restrict__ r,
                                               float* __restrict__ out) {
    int b = blockIdx.x;
    int tid = threadIdx.x;
    float v = r[b * 256 + tid];
    float sq = v * v;
#pragma unroll
    for (int o = 32; o > 0; o >>= 1) sq += __shfl_down(sq, o, 64);
    __shared__ float wsum[4];
    if ((tid & 63) == 0) wsum[tid >> 6] = sq;
    __syncthreads();
    float tot = wsum[0] + wsum[1] + wsum[2] + wsum[3];
    float scale = 1.f / fmaxf(sqrtf(tot), 1e-12f);
    out[b * 256 + tid] = v * scale;
}

extern "C" void kernel_launch(void* const* d_in, const int* in_sizes, int n_in,
                              void* d_out, int out_size, void* d_ws, size_t ws_size,
                              hipStream_t stream) {
    const float* x    = (const float*)d_in[0];
    const int*   len  = (const int*)d_in[1];
    const float* w1   = (const float*)d_in[2];
    const float* b1   = (const float*)d_in[3];
    const float* g1   = (const float*)d_in[4];
    const float* be1  = (const float*)d_in[5];
    const float* m1   = (const float*)d_in[6];
    const float* v1   = (const float*)d_in[7];
    const float* w2   = (const float*)d_in[8];
    const float* b2   = (const float*)d_in[9];
    const float* g2   = (const float*)d_in[10];
    const float* be2  = (const float*)d_in[11];
    const float* m2   = (const float*)d_in[12];
    const float* v2   = (const float*)d_in[13];
    const float* fcw  = (const float*)d_in[14];
    const float* fcb  = (const float*)d_in[15];
    const float* g3   = (const float*)d_in[16];
    const float* be3  = (const float*)d_in[17];
    const float* m3   = (const float*)d_in[18];
    const float* v3   = (const float*)d_in[19];

    char* ws = (char*)d_ws;
    int* off             = (int*)ws;                              // 17 ints
    unsigned short* w2b  = (unsigned short*)(ws + 256);           // 512 KB
    unsigned short* att1 = (unsigned short*)(ws + 524544);        // 16 MB
    unsigned short* e    = (unsigned short*)(ws + 17301760);      // 64 MB
    float* out2          = (float*)(ws + 84410624);               // 2 MB
    float* r             = (float*)(ws + 86507776);               // 16 KB
    float* out           = (float*)d_out;

    hipLaunchKernelGGL(k0_prep,  dim3(1024), dim3(256), 0, stream, w2, w2b, len, off);
    hipLaunchKernelGGL(k1_gemm1, dim3(512),  dim3(256), 0, stream, x, w1, b1, g1, be1, m1, v1, att1);
    hipLaunchKernelGGL(k2_gemm2, dim3(2048), dim3(256), 0, stream, att1, w2b, b2, g2, be2, m2, v2, e);
    hipLaunchKernelGGL(k3_pool,  dim3(2048), dim3(256), 0, stream, e, x, off, out2);
    hipLaunchKernelGGL(k4_fc,    dim3(128),  dim3(256), 0, stream, out2, fcw, fcb, g3, be3, m3, v3, r);
    hipLaunchKernelGGL(k5_norm,  dim3(16),   dim3(256), 0, stream, r, out);
}

// Round 2
// 208.799 us; speedup vs baseline: 2.2041x; 2.2041x over previous
//
#include <hip/hip_runtime.h>
#include <hip/hip_bf16.h>

typedef __bf16 bf16x8 __attribute__((ext_vector_type(8)));
typedef unsigned short u16x8 __attribute__((ext_vector_type(8)));
typedef float f32x4 __attribute__((ext_vector_type(4)));
typedef float f32x2 __attribute__((ext_vector_type(2)));

__device__ inline unsigned short f2bf(float f) {
    unsigned u = __builtin_bit_cast(unsigned, f);
    unsigned r = (u + 0x7fffu + ((u >> 16) & 1u)) >> 16;
    return (unsigned short)r;
}
__device__ inline float bf2f(unsigned short h) {
    unsigned u = ((unsigned)h) << 16;
    return __builtin_bit_cast(float, u);
}

// meta layout (ints): [0..16] seg offsets, [17] nch,
// [32..111] chunk_b, [112..191] chunk_start, [192..271] chunk_end,
// [272..287] per-b chunk range start, [288..303] per-b chunk range end
#define CHUNKR 512
#define MAXCH 80

// K0: cast w2 -> bf16; build segment/chunk meta
__global__ __launch_bounds__(256) void k0_prep(const float* __restrict__ w2,
                                               unsigned short* __restrict__ w2b,
                                               const int* __restrict__ length,
                                               int* __restrict__ meta) {
    int i = blockIdx.x * 256 + threadIdx.x;
    if (i < 1024 * 256) w2b[i] = f2bf(w2[i]);
    if (blockIdx.x == 0 && threadIdx.x == 0) {
        int acc = 0;
        for (int b = 0; b < 16; b++) { meta[b] = acc; acc += length[b]; }
        meta[16] = acc;
        int nch = 0;
        for (int b = 0; b < 16; b++) {
            meta[272 + b] = nch;
            for (int s = meta[b]; s < meta[b + 1]; s += CHUNKR) {
                int en = meta[b + 1] < s + CHUNKR ? meta[b + 1] : s + CHUNKR;
                meta[32 + nch] = b;
                meta[112 + nch] = s;
                meta[192 + nch] = en;
                nch++;
            }
            meta[288 + b] = nch;
        }
        meta[17] = nch;
    }
}

// K1: att1 = relu(bn1(x @ w1.T + b1)) -> bf16 [N,256]
__global__ __launch_bounds__(256) void k1_gemm1(const float* __restrict__ x,
                                                const float* __restrict__ w1,
                                                const float* __restrict__ b1,
                                                const float* __restrict__ g1,
                                                const float* __restrict__ be1,
                                                const float* __restrict__ m1,
                                                const float* __restrict__ v1,
                                                unsigned short* __restrict__ att1) {
    __shared__ float xs[64][33];
    int tid = threadIdx.x;
    int row0 = blockIdx.x * 64;
    for (int i = tid; i < 64 * 32; i += 256) {
        int rr = i >> 5, c = i & 31;
        xs[rr][c] = x[(row0 + rr) * 32 + c];
    }
    __syncthreads();
    int j = tid;
    float w[32];
#pragma unroll
    for (int c = 0; c < 32; c++) w[c] = w1[j * 32 + c];
    float s = g1[j] * rsqrtf(v1[j] + 1e-5f);
    float bias = (b1[j] - m1[j]) * s + be1[j];
    for (int rr = 0; rr < 64; rr++) {
        float acc = 0.f;
#pragma unroll
        for (int c = 0; c < 32; c++) acc = fmaf(xs[rr][c], w[c], acc);
        float t = fmaf(acc, s, bias);
        att1[(row0 + rr) * 256 + j] = f2bf(fmaxf(t, 0.f));
    }
}

// K2: e = exp(relu(bn2(att1 @ w2.T + b2))) -> bf16 [N,1024], MFMA bf16
__global__ __launch_bounds__(256) void k2_gemm2(const unsigned short* __restrict__ att1,
                                                const unsigned short* __restrict__ w2b,
                                                const float* __restrict__ b2,
                                                const float* __restrict__ g2,
                                                const float* __restrict__ be2,
                                                const float* __restrict__ m2,
                                                const float* __restrict__ v2,
                                                unsigned short* __restrict__ e) {
    int tid = threadIdx.x;
    int lane = tid & 63;
    int wave = tid >> 6;
    int wr = wave >> 1, wc = wave & 1;
    int bn = blockIdx.x & 255;
    int bk = blockIdx.x >> 8;
    int row0 = bn * 128 + wr * 64;
    int col0 = bk * 128 + wc * 64;
    int lr = lane & 15;
    int lk = (lane >> 4) * 8;
    f32x4 acc[4][4] = {};
    for (int ks = 0; ks < 256; ks += 32) {
        bf16x8 a[4], b[4];
#pragma unroll
        for (int m = 0; m < 4; m++)
            a[m] = *(const bf16x8*)(const void*)(att1 + (size_t)(row0 + m * 16 + lr) * 256 + ks + lk);
#pragma unroll
        for (int n = 0; n < 4; n++)
            b[n] = *(const bf16x8*)(const void*)(w2b + (size_t)(col0 + n * 16 + lr) * 256 + ks + lk);
#pragma unroll
        for (int m = 0; m < 4; m++)
#pragma unroll
            for (int n = 0; n < 4; n++)
                acc[m][n] = __builtin_amdgcn_mfma_f32_16x16x32_bf16(a[m], b[n], acc[m][n], 0, 0, 0);
    }
    int cr = (lane >> 4) * 4;
    int cc = lane & 15;
#pragma unroll
    for (int n = 0; n < 4; n++) {
        int k = col0 + n * 16 + cc;
        float s = g2[k] * rsqrtf(v2[k] + 1e-5f);
        float bias = (b2[k] - m2[k]) * s + be2[k];
#pragma unroll
        for (int m = 0; m < 4; m++) {
#pragma unroll
            for (int rg = 0; rg < 4; rg++) {
                int row = row0 + m * 16 + cr + rg;
                float t = fmaf(acc[m][n][rg], s, bias);
                t = fmaxf(t, 0.f);
                e[(size_t)row * 1024 + k] = f2bf(__expf(t));
            }
        }
    }
}

// K3a: per-chunk partial P[k][c] = sum_n e*x, partial S[k] = sum_n e
__global__ __launch_bounds__(256) void k3a_pool(const unsigned short* __restrict__ e,
                                                const float* __restrict__ x,
                                                const int* __restrict__ meta,
                                                float* __restrict__ pP,
                                                float* __restrict__ pS) {
    int ch = blockIdx.x >> 3, kt = blockIdx.x & 7;
    if (ch >= meta[17]) return;
    int n0 = meta[112 + ch], n1 = meta[192 + ch];
    int k0 = kt * 128;
    int tid = threadIdx.x;
    __shared__ float es[64][128];
    __shared__ float xs[64][32];
    int kg = tid >> 4;        // 0..15
    int c2 = (tid & 15) * 2;  // 0,2,..,30
    float acc[8][2] = {};
    float sa = 0.f;
    int nrb = (n1 - n0 + 63) >> 6;
    for (int rb = 0; rb < nrb; rb++) {
        int base = n0 + rb * 64;
        int rows = n1 - base;
        if (rows > 64) rows = 64;
#pragma unroll
        for (int it = 0; it < 4; it++) {
            int idx = it * 256 + tid;
            int r = idx >> 4, ksg = idx & 15;
            f32x4 v0 = {0, 0, 0, 0}, v1 = {0, 0, 0, 0};
            if (r < rows) {
                u16x8 ev = *(const u16x8*)(const void*)(e + (size_t)(base + r) * 1024 + k0 + ksg * 8);
                v0[0] = bf2f(ev[0]); v0[1] = bf2f(ev[1]); v0[2] = bf2f(ev[2]); v0[3] = bf2f(ev[3]);
                v1[0] = bf2f(ev[4]); v1[1] = bf2f(ev[5]); v1[2] = bf2f(ev[6]); v1[3] = bf2f(ev[7]);
            }
            *(f32x4*)&es[r][ksg * 8] = v0;
            *(f32x4*)&es[r][ksg * 8 + 4] = v1;
        }
#pragma unroll
        for (int it = 0; it < 2; it++) {
            int idx = it * 256 + tid;
            int r = idx >> 3, c4 = (idx & 7) * 4;
            f32x4 xv = {0, 0, 0, 0};
            if (r < rows) xv = *(const f32x4*)(const void*)(x + (size_t)(base + r) * 32 + c4);
            *(f32x4*)&xs[r][c4] = xv;
        }
        __syncthreads();
#pragma unroll 4
        for (int r = 0; r < 64; r++) {
            float xv0 = xs[r][c2];
            float xv1 = xs[r][c2 + 1];
            f32x4 e0 = *(f32x4*)&es[r][kg * 8];
            f32x4 e1 = *(f32x4*)&es[r][kg * 8 + 4];
#pragma unroll
            for (int kk = 0; kk < 4; kk++) {
                acc[kk][0] = fmaf(e0[kk], xv0, acc[kk][0]);
                acc[kk][1] = fmaf(e0[kk], xv1, acc[kk][1]);
                acc[4 + kk][0] = fmaf(e1[kk], xv0, acc[4 + kk][0]);
                acc[4 + kk][1] = fmaf(e1[kk], xv1, acc[4 + kk][1]);
            }
        }
        if (tid < 128) {
#pragma unroll 8
            for (int r = 0; r < 64; r++) sa += es[r][tid];
        }
        __syncthreads();
    }
    float* p = pP + (size_t)ch * 32768;
#pragma unroll
    for (int kk = 0; kk < 8; kk++) {
        int k = k0 + kg * 8 + kk;
        *(f32x2*)&p[k * 32 + c2] = f32x2{acc[kk][0], acc[kk][1]};
    }
    if (tid < 128) pS[ch * 1024 + k0 + tid] = sa;
}

// K3b: out2[b][k*32+c] = sum_ch P / (sum_ch S * len)
__global__ __launch_bounds__(256) void k3b_reduce(const float* __restrict__ pP,
                                                  const float* __restrict__ pS,
                                                  const int* __restrict__ meta,
                                                  float* __restrict__ out2) {
    int id = blockIdx.x * 256 + threadIdx.x;  // 0..524287
    int b = id >> 15, rem = id & 32767, k = rem >> 5;
    float P = 0.f, S = 0.f;
    int c0 = meta[272 + b], c1 = meta[288 + b];
    for (int ch = c0; ch < c1; ch++) {
        P += pP[(size_t)ch * 32768 + rem];
        S += pS[ch * 1024 + k];
    }
    float len = (float)(meta[b + 1] - meta[b]);
    out2[id] = P / (S * len);
}

// K4: r = bn3(out2 @ fcw.T + fcb)  [16,256]
__global__ __launch_bounds__(256) void k4_fc(const float* __restrict__ out2,
                                             const float* __restrict__ fcw,
                                             const float* __restrict__ fcb,
                                             const float* __restrict__ g3,
                                             const float* __restrict__ be3,
                                             const float* __restrict__ m3,
                                             const float* __restrict__ v3,
                                             float* __restrict__ r) {
    int jt = blockIdx.x >> 2;
    int bg = blockIdx.x & 3;
    int tid = threadIdx.x;
    float acc[4][8] = {};
    for (int i = 0; i < 128; i++) {
        int d = i * 256 + tid;
        float ov[4];
#pragma unroll
        for (int bb = 0; bb < 4; bb++) ov[bb] = out2[(bg * 4 + bb) * 32768 + d];
#pragma unroll
        for (int jj = 0; jj < 8; jj++) {
            float wv = fcw[(size_t)(jt * 8 + jj) * 32768 + d];
#pragma unroll
            for (int bb = 0; bb < 4; bb++) acc[bb][jj] = fmaf(ov[bb], wv, acc[bb][jj]);
        }
    }
    __shared__ float red[32][257];
#pragma unroll
    for (int bb = 0; bb < 4; bb++)
#pragma unroll
        for (int jj = 0; jj < 8; jj++)
            red[bb * 8 + jj][tid] = acc[bb][jj];
    __syncthreads();
    int row = tid >> 3, sg = tid & 7;
    float s = 0.f;
    for (int t = sg; t < 256; t += 8) s += red[row][t];
#pragma unroll
    for (int o = 4; o > 0; o >>= 1) s += __shfl_down(s, o, 8);
    if (sg == 0) {
        int bb = row >> 3, jj = row & 7;
        int j = jt * 8 + jj;
        int bidx = bg * 4 + bb;
        float sc = g3[j] * rsqrtf(v3[j] + 1e-5f);
        r[bidx * 256 + j] = (s + fcb[j] - m3[j]) * sc + be3[j];
    }
}

// K5: L2-normalize rows of r -> out
__global__ __launch_bounds__(256) void k5_norm(const float* __restrict__ r,
                                               float* __restrict__ out) {
    int b = blockIdx.x;
    int tid = threadIdx.x;
    float v = r[b * 256 + tid];
    float sq = v * v;
#pragma unroll
    for (int o = 32; o > 0; o >>= 1) sq += __shfl_down(sq, o, 64);
    __shared__ float wsum[4];
    if ((tid & 63) == 0) wsum[tid >> 6] = sq;
    __syncthreads();
    float tot = wsum[0] + wsum[1] + wsum[2] + wsum[3];
    float scale = 1.f / fmaxf(sqrtf(tot), 1e-12f);
    out[b * 256 + tid] = v * scale;
}

extern "C" void kernel_launch(void* const* d_in, const int* in_sizes, int n_in,
                              void* d_out, int out_size, void* d_ws, size_t ws_size,
                              hipStream_t stream) {
    const float* x    = (const float*)d_in[0];
    const int*   len  = (const int*)d_in[1];
    const float* w1   = (const float*)d_in[2];
    const float* b1   = (const float*)d_in[3];
    const float* g1   = (const float*)d_in[4];
    const float* be1  = (const float*)d_in[5];
    const float* m1   = (const float*)d_in[6];
    const float* v1   = (const float*)d_in[7];
    const float* w2   = (const float*)d_in[8];
    const float* b2   = (const float*)d_in[9];
    const float* g2   = (const float*)d_in[10];
    const float* be2  = (const float*)d_in[11];
    const float* m2   = (const float*)d_in[12];
    const float* v2   = (const float*)d_in[13];
    const float* fcw  = (const float*)d_in[14];
    const float* fcb  = (const float*)d_in[15];
    const float* g3   = (const float*)d_in[16];
    const float* be3  = (const float*)d_in[17];
    const float* m3   = (const float*)d_in[18];
    const float* v3   = (const float*)d_in[19];

    char* ws = (char*)d_ws;
    int* meta            = (int*)ws;                       // 4 KB
    unsigned short* w2b  = (unsigned short*)(ws + 4096);   // 512 KB -> ends 528384
    unsigned short* att1 = (unsigned short*)(ws + 528384); // 16 MB  -> ends 17305600
    // partials reuse att1's region (att1 dead after k2):
    float* pP            = (float*)(ws + 528384);              // 80*32768*4 = 10.5 MB
    float* pS            = (float*)(ws + 528384 + 10485760);   // 320 KB
    unsigned short* e    = (unsigned short*)(ws + 17305600);   // 64 MB -> ends 84414464
    float* out2          = (float*)(ws + 84414464);            // 2 MB  -> ends 86511616
    float* r             = (float*)(ws + 86511616);            // 16 KB
    float* out           = (float*)d_out;

    hipLaunchKernelGGL(k0_prep,   dim3(1024),       dim3(256), 0, stream, w2, w2b, len, meta);
    hipLaunchKernelGGL(k1_gemm1,  dim3(512),        dim3(256), 0, stream, x, w1, b1, g1, be1, m1, v1, att1);
    hipLaunchKernelGGL(k2_gemm2,  dim3(2048),       dim3(256), 0, stream, att1, w2b, b2, g2, be2, m2, v2, e);
    hipLaunchKernelGGL(k3a_pool,  dim3(MAXCH * 8),  dim3(256), 0, stream, e, x, meta, pP, pS);
    hipLaunchKernelGGL(k3b_reduce,dim3(2048),       dim3(256), 0, stream, pP, pS, meta, out2);
    hipLaunchKernelGGL(k4_fc,     dim3(128),        dim3(256), 0, stream, out2, fcw, fcb, g3, be3, m3, v3, r);
    hipLaunchKernelGGL(k5_norm,   dim3(16),         dim3(256), 0, stream, r, out);
}

// Round 3
// 192.900 us; speedup vs baseline: 2.3857x; 1.0824x over previous
//
#include <hip/hip_runtime.h>
#include <hip/hip_bf16.h>

typedef __bf16 bf16x8 __attribute__((ext_vector_type(8)));
typedef float f32x4 __attribute__((ext_vector_type(4)));

__device__ inline unsigned short f2bf(float f) {
    unsigned u = __builtin_bit_cast(unsigned, f);
    unsigned r = (u + 0x7fffu + ((u >> 16) & 1u)) >> 16;
    return (unsigned short)r;
}

__device__ inline void gload_lds16(const void* g, void* l) {
    __builtin_amdgcn_global_load_lds((const __attribute__((address_space(1))) void*)g,
                                     (__attribute__((address_space(3))) void*)l, 16, 0, 0);
}

// meta: [0..16] seg offsets, [17] nch, [304..575] chunk_start, [576..847] chunk_end,
//       [848..863] per-b chunk start, [864..879] per-b chunk end
#define MAXCH 272

// K0: cast w2 -> bf16; build segment/chunk meta (128-row chunks)
__global__ __launch_bounds__(256) void k0_prep(const float* __restrict__ w2,
                                               unsigned short* __restrict__ w2b,
                                               const int* __restrict__ length,
                                               int* __restrict__ meta) {
    int i = blockIdx.x * 256 + threadIdx.x;
    if (i < 1024 * 256) w2b[i] = f2bf(w2[i]);
    if (blockIdx.x == 0 && threadIdx.x == 0) {
        int acc = 0;
        for (int b = 0; b < 16; b++) { meta[b] = acc; acc += length[b]; }
        meta[16] = acc;
        int nch = 0;
        for (int b = 0; b < 16; b++) {
            meta[848 + b] = nch;
            for (int s = meta[b]; s < meta[b + 1]; s += 128) {
                int en = meta[b + 1] < s + 128 ? meta[b + 1] : s + 128;
                meta[304 + nch] = s;
                meta[576 + nch] = en;
                nch++;
            }
            meta[864 + b] = nch;
        }
        meta[17] = nch;
    }
}

// K1: att1 = relu(bn1(x @ w1.T + b1)) -> bf16 [N,256]
__global__ __launch_bounds__(256) void k1_gemm1(const float* __restrict__ x,
                                                const float* __restrict__ w1,
                                                const float* __restrict__ b1,
                                                const float* __restrict__ g1,
                                                const float* __restrict__ be1,
                                                const float* __restrict__ m1,
                                                const float* __restrict__ v1,
                                                unsigned short* __restrict__ att1) {
    __shared__ float xs[64][33];
    int tid = threadIdx.x;
    int row0 = blockIdx.x * 64;
    for (int i = tid; i < 64 * 32; i += 256) {
        int rr = i >> 5, c = i & 31;
        xs[rr][c] = x[(row0 + rr) * 32 + c];
    }
    __syncthreads();
    int j = tid;
    float w[32];
#pragma unroll
    for (int c = 0; c < 32; c++) w[c] = w1[j * 32 + c];
    float s = g1[j] * rsqrtf(v1[j] + 1e-5f);
    float bias = (b1[j] - m1[j]) * s + be1[j];
    for (int rr = 0; rr < 64; rr++) {
        float acc = 0.f;
#pragma unroll
        for (int c = 0; c < 32; c++) acc = fmaf(xs[rr][c], w[c], acc);
        float t = fmaf(acc, s, bias);
        att1[(row0 + rr) * 256 + j] = f2bf(fmaxf(t, 0.f));
    }
}

// K23: fused GEMM2 (att1 @ w2.T -> e) + segment-partial pooling (P = e^T x, S = e^T 1).
// Grid: (272 chunks, 8 k-tiles). Per block: 128 rows (one segment-aligned chunk) x 128 k.
__global__ __launch_bounds__(256) void k23_fused(const unsigned short* __restrict__ att1,
                                                 const unsigned short* __restrict__ w2b,
                                                 const float* __restrict__ x,
                                                 const int* __restrict__ meta,
                                                 const float* __restrict__ b2,
                                                 const float* __restrict__ g2,
                                                 const float* __restrict__ be2,
                                                 const float* __restrict__ m2,
                                                 const float* __restrict__ v2,
                                                 float* __restrict__ pP,
                                                 float* __restrict__ pS) {
    __shared__ __align__(16) unsigned short As[2][128 * 64];  // 32 KB dbuf; reused as eT[128][128]
    __shared__ __align__(16) unsigned short xT[48 * 128];     // 12 KB  (c=32 is the ones-column)
    int ch = blockIdx.x, kt = blockIdx.y;
    if (ch >= meta[17]) return;
    int n0 = meta[304 + ch];
    int rows = meta[576 + ch] - n0;
    int col0 = kt * 128;
    int tid = threadIdx.x, lane = tid & 63, wave = tid >> 6;
    int lr = lane & 15, s16 = lane >> 4;

    // ---- stage xT[c][n] (bf16, swizzled) ----
    {
        int c = tid & 63, nb = tid >> 6;
        if (c < 48) {
            for (int nn = 0; nn < 32; nn++) {
                int n = nb * 32 + nn;
                float v = 0.f;
                if (c < 32) { if (n < rows) v = x[(size_t)(n0 + n) * 32 + c]; }
                else if (c == 32) { v = (n < rows) ? 1.f : 0.f; }
                int byte = c * 256 + (((n * 2) ^ ((c & 7) << 4)));
                *(unsigned short*)((char*)xT + byte) = f2bf(v);
            }
        }
    }

    // ---- stage K-tile of att1 into As[buf] (swizzled via pre-swizzled source) ----
    auto stage = [&](int t, int buf) {
#pragma unroll
        for (int it = 0; it < 4; it++) {
            int idx = it * 256 + tid;
            int row = idx >> 3, slot = idx & 7;
            int srow = row < rows ? row : rows - 1;
            int g = slot ^ (row & 7);
            const void* src = att1 + (size_t)(n0 + srow) * 256 + t * 64 + g * 8;
            void* dst = (char*)As + buf * 16384 + it * 4096 + wave * 1024;
            gload_lds16(src, dst);
        }
    };

    stage(0, 0);
    __syncthreads();

    int wr = wave >> 1, wc = wave & 1;
    f32x4 acc[4][4] = {};
    int cur = 0;
    for (int t = 0; t < 4; t++) {
        if (t < 3) stage(t + 1, cur ^ 1);
        const char* Ab = (const char*)As + cur * 16384;
#pragma unroll
        for (int kk = 0; kk < 2; kk++) {
            bf16x8 a[4], b[4];
#pragma unroll
            for (int m = 0; m < 4; m++) {
                int row = wr * 64 + m * 16 + lr;
                int slot = (kk * 4 + s16) ^ (row & 7);
                a[m] = *(const bf16x8*)(const void*)(Ab + row * 128 + slot * 16);
            }
            int ks = t * 64 + kk * 32;
#pragma unroll
            for (int n = 0; n < 4; n++)
                b[n] = *(const bf16x8*)(const void*)(w2b + (size_t)(col0 + wc * 64 + n * 16 + lr) * 256 + ks + s16 * 8);
#pragma unroll
            for (int m = 0; m < 4; m++)
#pragma unroll
                for (int n = 0; n < 4; n++)
                    acc[m][n] = __builtin_amdgcn_mfma_f32_16x16x32_bf16(a[m], b[n], acc[m][n], 0, 0, 0);
        }
        __syncthreads();
        cur ^= 1;
    }

    // ---- epilogue: e = exp(relu(bn2(acc))), write TRANSPOSED eT[k][n] into As (b64, swizzled) ----
    char* eT = (char*)As;
#pragma unroll
    for (int nf = 0; nf < 4; nf++) {
        int k = wc * 64 + nf * 16 + lr;
        int kg = col0 + k;
        float sc = g2[kg] * rsqrtf(v2[kg] + 1e-5f);
        float bias = (b2[kg] - m2[kg]) * sc + be2[kg];
#pragma unroll
        for (int m = 0; m < 4; m++) {
            int nbase = wr * 64 + m * 16 + s16 * 4;
            unsigned long long pk = 0;
#pragma unroll
            for (int rg = 0; rg < 4; rg++) {
                float tt = fmaf(acc[m][nf][rg], sc, bias);
                float ev = __expf(fmaxf(tt, 0.f));
                unsigned short h = (nbase + rg < rows) ? f2bf(ev) : (unsigned short)0;
                pk |= ((unsigned long long)h) << (16 * rg);
            }
            int byte = k * 256 + ((nbase * 2) ^ ((k & 7) << 4));
            *(unsigned long long*)(eT + byte) = pk;
        }
    }
    __syncthreads();

    // ---- pool MFMA: P[k][c] = sum_n eT[k][n] * xT[c][n]; c=32 gives S[k] ----
    f32x4 pacc[2][3] = {};
    for (int nc = 0; nc < 128; nc += 32) {
        bf16x8 ea[2], xb[3];
#pragma unroll
        for (int i = 0; i < 2; i++) {
            int k = (wave * 2 + i) * 16 + lr;
            int byte = k * 256 + (((nc + s16 * 8) * 2) ^ ((k & 7) << 4));
            ea[i] = *(const bf16x8*)(const void*)(eT + byte);
        }
#pragma unroll
        for (int j = 0; j < 3; j++) {
            int c = j * 16 + lr;
            int byte = c * 256 + (((nc + s16 * 8) * 2) ^ ((c & 7) << 4));
            xb[j] = *(const bf16x8*)(const void*)((const char*)xT + byte);
        }
#pragma unroll
        for (int i = 0; i < 2; i++)
#pragma unroll
            for (int j = 0; j < 3; j++)
                pacc[i][j] = __builtin_amdgcn_mfma_f32_16x16x32_bf16(ea[i], xb[j], pacc[i][j], 0, 0, 0);
    }

    float* pPc = pP + (size_t)ch * 32768;
#pragma unroll
    for (int i = 0; i < 2; i++) {
#pragma unroll
        for (int j = 0; j < 3; j++) {
            int c = j * 16 + lr;
#pragma unroll
            for (int rg = 0; rg < 4; rg++) {
                int k = (wave * 2 + i) * 16 + s16 * 4 + rg;
                float v = pacc[i][j][rg];
                if (c < 32) pPc[(col0 + k) * 32 + c] = v;
                else if (c == 32) pS[ch * 1024 + col0 + k] = v;
            }
        }
    }
}

// K3b: out2[b][k*32+c] = sum_ch P / (sum_ch S * len)
__global__ __launch_bounds__(256) void k3b_reduce(const float* __restrict__ pP,
                                                  const float* __restrict__ pS,
                                                  const int* __restrict__ meta,
                                                  float* __restrict__ out2) {
    int id = blockIdx.x * 256 + threadIdx.x;
    int b = id >> 15, rem = id & 32767, k = rem >> 5;
    float P = 0.f, S = 0.f;
    int c0 = meta[848 + b], c1 = meta[864 + b];
    for (int ch = c0; ch < c1; ch++) {
        P += pP[(size_t)ch * 32768 + rem];
        S += pS[ch * 1024 + k];
    }
    float len = (float)(meta[b + 1] - meta[b]);
    out2[id] = P / (S * len);
}

// K4: r = bn3(out2 @ fcw.T + fcb)  [16,256]
__global__ __launch_bounds__(256) void k4_fc(const float* __restrict__ out2,
                                             const float* __restrict__ fcw,
                                             const float* __restrict__ fcb,
                                             const float* __restrict__ g3,
                                             const float* __restrict__ be3,
                                             const float* __restrict__ m3,
                                             const float* __restrict__ v3,
                                             float* __restrict__ r) {
    int jt = blockIdx.x >> 2;
    int bg = blockIdx.x & 3;
    int tid = threadIdx.x;
    float acc[4][8] = {};
    for (int i = 0; i < 128; i++) {
        int d = i * 256 + tid;
        float ov[4];
#pragma unroll
        for (int bb = 0; bb < 4; bb++) ov[bb] = out2[(bg * 4 + bb) * 32768 + d];
#pragma unroll
        for (int jj = 0; jj < 8; jj++) {
            float wv = fcw[(size_t)(jt * 8 + jj) * 32768 + d];
#pragma unroll
            for (int bb = 0; bb < 4; bb++) acc[bb][jj] = fmaf(ov[bb], wv, acc[bb][jj]);
        }
    }
    __shared__ float red[32][257];
#pragma unroll
    for (int bb = 0; bb < 4; bb++)
#pragma unroll
        for (int jj = 0; jj < 8; jj++)
            red[bb * 8 + jj][tid] = acc[bb][jj];
    __syncthreads();
    int row = tid >> 3, sg = tid & 7;
    float s = 0.f;
    for (int t = sg; t < 256; t += 8) s += red[row][t];
#pragma unroll
    for (int o = 4; o > 0; o >>= 1) s += __shfl_down(s, o, 8);
    if (sg == 0) {
        int bb = row >> 3, jj = row & 7;
        int j = jt * 8 + jj;
        int bidx = bg * 4 + bb;
        float sc = g3[j] * rsqrtf(v3[j] + 1e-5f);
        r[bidx * 256 + j] = (s + fcb[j] - m3[j]) * sc + be3[j];
    }
}

// K5: L2-normalize rows of r -> out
__global__ __launch_bounds__(256) void k5_norm(const float* __restrict__ r,
                                               float* __restrict__ out) {
    int b = blockIdx.x;
    int tid = threadIdx.x;
    float v = r[b * 256 + tid];
    float sq = v * v;
#pragma unroll
    for (int o = 32; o > 0; o >>= 1) sq += __shfl_down(sq, o, 64);
    __shared__ float wsum[4];
    if ((tid & 63) == 0) wsum[tid >> 6] = sq;
    __syncthreads();
    float tot = wsum[0] + wsum[1] + wsum[2] + wsum[3];
    float scale = 1.f / fmaxf(sqrtf(tot), 1e-12f);
    out[b * 256 + tid] = v * scale;
}

extern "C" void kernel_launch(void* const* d_in, const int* in_sizes, int n_in,
                              void* d_out, int out_size, void* d_ws, size_t ws_size,
                              hipStream_t stream) {
    const float* x    = (const float*)d_in[0];
    const int*   len  = (const int*)d_in[1];
    const float* w1   = (const float*)d_in[2];
    const float* b1   = (const float*)d_in[3];
    const float* g1   = (const float*)d_in[4];
    const float* be1  = (const float*)d_in[5];
    const float* m1   = (const float*)d_in[6];
    const float* v1   = (const float*)d_in[7];
    const float* w2   = (const float*)d_in[8];
    const float* b2   = (const float*)d_in[9];
    const float* g2   = (const float*)d_in[10];
    const float* be2  = (const float*)d_in[11];
    const float* m2   = (const float*)d_in[12];
    const float* v2   = (const float*)d_in[13];
    const float* fcw  = (const float*)d_in[14];
    const float* fcb  = (const float*)d_in[15];
    const float* g3   = (const float*)d_in[16];
    const float* be3  = (const float*)d_in[17];
    const float* m3   = (const float*)d_in[18];
    const float* v3   = (const float*)d_in[19];

    char* ws = (char*)d_ws;
    int* meta            = (int*)ws;                           // 4 KB
    unsigned short* w2b  = (unsigned short*)(ws + 4096);       // 512 KB -> 528384
    unsigned short* att1 = (unsigned short*)(ws + 528384);     // 16 MB  -> 17305600
    float* pP            = (float*)(ws + 17305600);            // 272*32768*4 = 35.65 MB -> 52957184
    float* pS            = (float*)(ws + 52957184);            // 272*1024*4 = 1.1 MB -> 54071296
    float* out2          = (float*)(ws + 54071296);            // 2 MB -> 56168448
    float* r             = (float*)(ws + 56168448);            // 16 KB
    float* out           = (float*)d_out;

    hipLaunchKernelGGL(k0_prep,    dim3(1024),        dim3(256), 0, stream, w2, w2b, len, meta);
    hipLaunchKernelGGL(k1_gemm1,   dim3(512),         dim3(256), 0, stream, x, w1, b1, g1, be1, m1, v1, att1);
    hipLaunchKernelGGL(k23_fused,  dim3(MAXCH, 8),    dim3(256), 0, stream, att1, w2b, x, meta, b2, g2, be2, m2, v2, pP, pS);
    hipLaunchKernelGGL(k3b_reduce, dim3(2048),        dim3(256), 0, stream, pP, pS, meta, out2);
    hipLaunchKernelGGL(k4_fc,      dim3(128),         dim3(256), 0, stream, out2, fcw, fcb, g3, be3, m3, v3, r);
    hipLaunchKernelGGL(k5_norm,    dim3(16),          dim3(256), 0, stream, r, out);
}

// Round 4
// 179.519 us; speedup vs baseline: 2.5636x; 1.0745x over previous
//
#include <hip/hip_runtime.h>
#include <hip/hip_bf16.h>

typedef __bf16 bf16x8 __attribute__((ext_vector_type(8)));
typedef float f32x4 __attribute__((ext_vector_type(4)));

__device__ inline unsigned short f2bf(float f) {
    unsigned u = __builtin_bit_cast(unsigned, f);
    unsigned r = (u + 0x7fffu + ((u >> 16) & 1u)) >> 16;
    return (unsigned short)r;
}

__device__ inline void gload_lds16(const void* g, void* l) {
    __builtin_amdgcn_global_load_lds((const __attribute__((address_space(1))) void*)g,
                                     (__attribute__((address_space(3))) void*)l, 16, 0, 0);
}

// meta: [0..16] seg offsets, [17] nch, [304..575] chunk_start, [576..847] chunk_end,
//       [848..863] per-b chunk start, [864..879] per-b chunk end
#define MAXCH 272

// K0: cast w2 -> bf16; build segment/chunk meta (wave-parallel, register-only)
__global__ __launch_bounds__(256) void k0_prep(const float* __restrict__ w2,
                                               unsigned short* __restrict__ w2b,
                                               const int* __restrict__ length,
                                               int* __restrict__ meta) {
    int i = blockIdx.x * 256 + threadIdx.x;
    if (i < 1024 * 256) w2b[i] = f2bf(w2[i]);
    if (blockIdx.x == 0 && threadIdx.x < 64) {
        int lane = threadIdx.x;
        int b = lane & 15;
        int len = length[b];
        int off = 0, chbase = 0, nch = 0;
        int nchb = (len + 127) >> 7;
#pragma unroll
        for (int j = 0; j < 16; j++) {
            int lj = __shfl(len, j, 64);
            int nj = __shfl(nchb, j, 64);
            if (j < b) { off += lj; chbase += nj; }
            nch += nj;
        }
        int total = __shfl(off + len, 15, 64);
        if (lane < 16) {
            meta[b] = off;
            meta[848 + b] = chbase;
            meta[864 + b] = chbase + nchb;
            if (b == 0) { meta[16] = total; meta[17] = nch; }
            for (int t = 0; t < nchb; t++) {
                int s = off + t * 128;
                int en = off + len < s + 128 ? off + len : s + 128;
                meta[304 + chbase + t] = s;
                meta[576 + chbase + t] = en;
            }
        }
    }
}

// K1: att1 = relu(bn1(x @ w1.T + b1)) -> bf16 [N,256]
__global__ __launch_bounds__(256) void k1_gemm1(const float* __restrict__ x,
                                                const float* __restrict__ w1,
                                                const float* __restrict__ b1,
                                                const float* __restrict__ g1,
                                                const float* __restrict__ be1,
                                                const float* __restrict__ m1,
                                                const float* __restrict__ v1,
                                                unsigned short* __restrict__ att1) {
    __shared__ float xs[64][33];
    int tid = threadIdx.x;
    int row0 = blockIdx.x * 64;
    for (int i = tid; i < 64 * 32; i += 256) {
        int rr = i >> 5, c = i & 31;
        xs[rr][c] = x[(row0 + rr) * 32 + c];
    }
    __syncthreads();
    int j = tid;
    float w[32];
#pragma unroll
    for (int c = 0; c < 32; c++) w[c] = w1[j * 32 + c];
    float s = g1[j] * rsqrtf(v1[j] + 1e-5f);
    float bias = (b1[j] - m1[j]) * s + be1[j];
    for (int rr = 0; rr < 64; rr++) {
        float acc = 0.f;
#pragma unroll
        for (int c = 0; c < 32; c++) acc = fmaf(xs[rr][c], w[c], acc);
        float t = fmaf(acc, s, bias);
        att1[(row0 + rr) * 256 + j] = f2bf(fmaxf(t, 0.f));
    }
}

// K23: fused GEMM2 + segment-partial pooling. Whole K=256 staged once; 3 barriers total.
__global__ __launch_bounds__(256, 2) void k23_fused(const unsigned short* __restrict__ att1,
                                                    const unsigned short* __restrict__ w2b,
                                                    const float* __restrict__ x,
                                                    const int* __restrict__ meta,
                                                    const float* __restrict__ b2,
                                                    const float* __restrict__ g2,
                                                    const float* __restrict__ be2,
                                                    const float* __restrict__ m2,
                                                    const float* __restrict__ v2,
                                                    float* __restrict__ pP,
                                                    float* __restrict__ pS) {
    __shared__ __align__(16) unsigned short As[128 * 256];  // 64 KB; reused as eT[128][128] after GEMM
    __shared__ __align__(16) unsigned short xT[48 * 128];   // 12 KB  (c=32 is the ones-column)
    int ch = blockIdx.x, kt = blockIdx.y;
    if (ch >= meta[17]) return;
    int n0 = meta[304 + ch];
    int rows = meta[576 + ch] - n0;
    int col0 = kt * 128;
    int tid = threadIdx.x, lane = tid & 63, wave = tid >> 6;
    int lr = lane & 15, s16 = lane >> 4;

    // ---- stage full att1 chunk [128 rows][K=256] into As, XOR-swizzled 16B slots ----
    // linear dst idx = it*256+tid (16B granules); row = idx>>5, phys slot ps = idx&31,
    // logical slot = ps ^ (row&31) -> pre-swizzled SOURCE, linear LDS dest.
#pragma unroll
    for (int it = 0; it < 16; it++) {
        int idx = it * 256 + tid;
        int row = idx >> 5, ps = idx & 31;
        int sl = ps ^ (row & 31);
        int srow = row < rows ? row : rows - 1;
        gload_lds16(att1 + (size_t)(n0 + srow) * 256 + sl * 8,
                    (char*)As + it * 4096 + wave * 1024);
    }

    // ---- stage xT[c][n] (bf16, swizzled) ----
    {
        int c = tid & 63, nb = tid >> 6;
        if (c < 48) {
            for (int nn = 0; nn < 32; nn++) {
                int n = nb * 32 + nn;
                float v = 0.f;
                if (c < 32) { if (n < rows) v = x[(size_t)(n0 + n) * 32 + c]; }
                else if (c == 32) { v = (n < rows) ? 1.f : 0.f; }
                int byte = c * 256 + (((n * 2) ^ ((c & 7) << 4)));
                *(unsigned short*)((char*)xT + byte) = f2bf(v);
            }
        }
    }
    __syncthreads();  // drains gload_lds (vmcnt 0) + xT writes

    // ---- main GEMM: 128 MFMA per wave, no barriers ----
    int wr = wave >> 1, wc = wave & 1;
    f32x4 acc[4][4] = {};
#pragma unroll
    for (int kk = 0; kk < 8; kk++) {
        bf16x8 a[4], b[4];
#pragma unroll
        for (int m = 0; m < 4; m++) {
            int row = wr * 64 + m * 16 + lr;
            int ps = (kk * 4 + s16) ^ (row & 31);
            a[m] = *(const bf16x8*)(const void*)((const char*)As + row * 512 + ps * 16);
        }
#pragma unroll
        for (int n = 0; n < 4; n++)
            b[n] = *(const bf16x8*)(const void*)(w2b + (size_t)(col0 + wc * 64 + n * 16 + lr) * 256 + kk * 32 + s16 * 8);
#pragma unroll
        for (int m = 0; m < 4; m++)
#pragma unroll
            for (int n = 0; n < 4; n++)
                acc[m][n] = __builtin_amdgcn_mfma_f32_16x16x32_bf16(a[m], b[n], acc[m][n], 0, 0, 0);
    }
    __syncthreads();  // all waves done reading As before eT overwrite

    // ---- epilogue: e = exp(relu(bn2(acc))), write TRANSPOSED eT[k][n] (b64, swizzled) ----
    char* eT = (char*)As;
#pragma unroll
    for (int nf = 0; nf < 4; nf++) {
        int k = wc * 64 + nf * 16 + lr;
        int kg = col0 + k;
        float sc = g2[kg] * rsqrtf(v2[kg] + 1e-5f);
        float bias = (b2[kg] - m2[kg]) * sc + be2[kg];
#pragma unroll
        for (int m = 0; m < 4; m++) {
            int nbase = wr * 64 + m * 16 + s16 * 4;
            unsigned long long pk = 0;
#pragma unroll
            for (int rg = 0; rg < 4; rg++) {
                float tt = fmaf(acc[m][nf][rg], sc, bias);
                float ev = __expf(fmaxf(tt, 0.f));
                unsigned short h = (nbase + rg < rows) ? f2bf(ev) : (unsigned short)0;
                pk |= ((unsigned long long)h) << (16 * rg);
            }
            int byte = k * 256 + ((nbase * 2) ^ ((k & 7) << 4));
            *(unsigned long long*)(eT + byte) = pk;
        }
    }
    __syncthreads();

    // ---- pool MFMA: P[k][c] = sum_n eT[k][n] * xT[c][n]; c=32 gives S[k] ----
    f32x4 pacc[2][3] = {};
#pragma unroll
    for (int nc = 0; nc < 128; nc += 32) {
        bf16x8 ea[2], xb[3];
#pragma unroll
        for (int i = 0; i < 2; i++) {
            int k = (wave * 2 + i) * 16 + lr;
            int byte = k * 256 + (((nc + s16 * 8) * 2) ^ ((k & 7) << 4));
            ea[i] = *(const bf16x8*)(const void*)(eT + byte);
        }
#pragma unroll
        for (int j = 0; j < 3; j++) {
            int c = j * 16 + lr;
            int byte = c * 256 + (((nc + s16 * 8) * 2) ^ ((c & 7) << 4));
            xb[j] = *(const bf16x8*)(const void*)((const char*)xT + byte);
        }
#pragma unroll
        for (int i = 0; i < 2; i++)
#pragma unroll
            for (int j = 0; j < 3; j++)
                pacc[i][j] = __builtin_amdgcn_mfma_f32_16x16x32_bf16(ea[i], xb[j], pacc[i][j], 0, 0, 0);
    }

    float* pPc = pP + (size_t)ch * 32768;
#pragma unroll
    for (int i = 0; i < 2; i++) {
#pragma unroll
        for (int j = 0; j < 3; j++) {
            int c = j * 16 + lr;
#pragma unroll
            for (int rg = 0; rg < 4; rg++) {
                int k = (wave * 2 + i) * 16 + s16 * 4 + rg;
                float v = pacc[i][j][rg];
                if (c < 32) pPc[(col0 + k) * 32 + c] = v;
                else if (c == 32) pS[ch * 1024 + col0 + k] = v;
            }
        }
    }
}

// K3b: out2[b][k*32+c] = sum_ch P / (sum_ch S * len)
__global__ __launch_bounds__(256) void k3b_reduce(const float* __restrict__ pP,
                                                  const float* __restrict__ pS,
                                                  const int* __restrict__ meta,
                                                  float* __restrict__ out2) {
    int id = blockIdx.x * 256 + threadIdx.x;
    int b = id >> 15, rem = id & 32767, k = rem >> 5;
    float P = 0.f, S = 0.f;
    int c0 = meta[848 + b], c1 = meta[864 + b];
    for (int ch = c0; ch < c1; ch++) {
        P += pP[(size_t)ch * 32768 + rem];
        S += pS[ch * 1024 + k];
    }
    float len = (float)(meta[b + 1] - meta[b]);
    out2[id] = P / (S * len);
}

// K4: r = bn3(out2 @ fcw.T + fcb)  [16,256]
__global__ __launch_bounds__(256) void k4_fc(const float* __restrict__ out2,
                                             const float* __restrict__ fcw,
                                             const float* __restrict__ fcb,
                                             const float* __restrict__ g3,
                                             const float* __restrict__ be3,
                                             const float* __restrict__ m3,
                                             const float* __restrict__ v3,
                                             float* __restrict__ r) {
    int jt = blockIdx.x >> 2;
    int bg = blockIdx.x & 3;
    int tid = threadIdx.x;
    float acc[4][8] = {};
    for (int i = 0; i < 128; i++) {
        int d = i * 256 + tid;
        float ov[4];
#pragma unroll
        for (int bb = 0; bb < 4; bb++) ov[bb] = out2[(bg * 4 + bb) * 32768 + d];
#pragma unroll
        for (int jj = 0; jj < 8; jj++) {
            float wv = fcw[(size_t)(jt * 8 + jj) * 32768 + d];
#pragma unroll
            for (int bb = 0; bb < 4; bb++) acc[bb][jj] = fmaf(ov[bb], wv, acc[bb][jj]);
        }
    }
    __shared__ float red[32][257];
#pragma unroll
    for (int bb = 0; bb < 4; bb++)
#pragma unroll
        for (int jj = 0; jj < 8; jj++)
            red[bb * 8 + jj][tid] = acc[bb][jj];
    __syncthreads();
    int row = tid >> 3, sg = tid & 7;
    float s = 0.f;
    for (int t = sg; t < 256; t += 8) s += red[row][t];
#pragma unroll
    for (int o = 4; o > 0; o >>= 1) s += __shfl_down(s, o, 8);
    if (sg == 0) {
        int bb = row >> 3, jj = row & 7;
        int j = jt * 8 + jj;
        int bidx = bg * 4 + bb;
        float sc = g3[j] * rsqrtf(v3[j] + 1e-5f);
        r[bidx * 256 + j] = (s + fcb[j] - m3[j]) * sc + be3[j];
    }
}

// K5: L2-normalize rows of r -> out
__global__ __launch_bounds__(256) void k5_norm(const float* __restrict__ r,
                                               float* __restrict__ out) {
    int b = blockIdx.x;
    int tid = threadIdx.x;
    float v = r[b * 256 + tid];
    float sq = v * v;
#pragma unroll
    for (int o = 32; o > 0; o >>= 1) sq += __shfl_down(sq, o, 64);
    __shared__ float wsum[4];
    if ((tid & 63) == 0) wsum[tid >> 6] = sq;
    __syncthreads();
    float tot = wsum[0] + wsum[1] + wsum[2] + wsum[3];
    float scale = 1.f / fmaxf(sqrtf(tot), 1e-12f);
    out[b * 256 + tid] = v * scale;
}

extern "C" void kernel_launch(void* const* d_in, const int* in_sizes, int n_in,
                              void* d_out, int out_size, void* d_ws, size_t ws_size,
                              hipStream_t stream) {
    const float* x    = (const float*)d_in[0];
    const int*   len  = (const int*)d_in[1];
    const float* w1   = (const float*)d_in[2];
    const float* b1   = (const float*)d_in[3];
    const float* g1   = (const float*)d_in[4];
    const float* be1  = (const float*)d_in[5];
    const float* m1   = (const float*)d_in[6];
    const float* v1   = (const float*)d_in[7];
    const float* w2   = (const float*)d_in[8];
    const float* b2   = (const float*)d_in[9];
    const float* g2   = (const float*)d_in[10];
    const float* be2  = (const float*)d_in[11];
    const float* m2   = (const float*)d_in[12];
    const float* v2   = (const float*)d_in[13];
    const float* fcw  = (const float*)d_in[14];
    const float* fcb  = (const float*)d_in[15];
    const float* g3   = (const float*)d_in[16];
    const float* be3  = (const float*)d_in[17];
    const float* m3   = (const float*)d_in[18];
    const float* v3   = (const float*)d_in[19];

    char* ws = (char*)d_ws;
    int* meta            = (int*)ws;                           // 4 KB
    unsigned short* w2b  = (unsigned short*)(ws + 4096);       // 512 KB -> 528384
    unsigned short* att1 = (unsigned short*)(ws + 528384);     // 16 MB  -> 17305600
    float* pP            = (float*)(ws + 17305600);            // 35.65 MB -> 52957184
    float* pS            = (float*)(ws + 52957184);            // 1.1 MB -> 54071296
    float* out2          = (float*)(ws + 54071296);            // 2 MB -> 56168448
    float* r             = (float*)(ws + 56168448);            // 16 KB
    float* out           = (float*)d_out;

    hipLaunchKernelGGL(k0_prep,    dim3(1024),     dim3(256), 0, stream, w2, w2b, len, meta);
    hipLaunchKernelGGL(k1_gemm1,   dim3(512),      dim3(256), 0, stream, x, w1, b1, g1, be1, m1, v1, att1);
    hipLaunchKernelGGL(k23_fused,  dim3(MAXCH, 8), dim3(256), 0, stream, att1, w2b, x, meta, b2, g2, be2, m2, v2, pP, pS);
    hipLaunchKernelGGL(k3b_reduce, dim3(2048),     dim3(256), 0, stream, pP, pS, meta, out2);
    hipLaunchKernelGGL(k4_fc,      dim3(128),      dim3(256), 0, stream, out2, fcw, fcb, g3, be3, m3, v3, r);
    hipLaunchKernelGGL(k5_norm,    dim3(16),       dim3(256), 0, stream, r, out);
}